// Round 6
// baseline (164.976 us; speedup 1.0000x reference)
//
#include <hip/hip_runtime.h>
#include <hip/hip_bf16.h>

#define LEN 128
#define NB 32
#define NC 16
#define NU 16
#define NK 5
#define KC 80          // (k,c) pairs
#define KCP 96         // padded K for stage2

typedef unsigned int uint32;
typedef unsigned short ushort16;
typedef __attribute__((ext_vector_type(8))) short bf16x8;
typedef __attribute__((ext_vector_type(4))) float f32x4;

#define MFMA(a, b, c) __builtin_amdgcn_mfma_f32_16x16x32_bf16(a, b, c, 0, 0, 0)

// XOR swizzle of the 16B-unit index (low 4 bits) within a row.
#define SIG(r) (((r) & 15) ^ (((r) >> 3) & 15))

static __device__ inline ushort16 f2bf(float f) {
    union { float f; uint32 u; } v; v.f = f;
    uint32 u = v.u;
    uint32 r = (u + 0x7fffu + ((u >> 16) & 1u)) >> 16;   // RNE
    return (ushort16)r;
}
static __device__ inline uint32 pkbf(float a, float b) {   // low=a, high=b (verified r0-r5)
    return (uint32)f2bf(a) | ((uint32)f2bf(b) << 16);
}
static __device__ inline bf16x8 frag16(const void* p) {    // 16B-aligned
    return *(const bf16x8*)p;
}

// ---------------- kprep: blocks 0..511 = x->xF transpose; 512..1181 = const operands ----------------
__global__ __launch_bounds__(256) void kprep(const float* __restrict__ x,
                                             const float* __restrict__ coefs,
                                             const float* __restrict__ cheb1,
                                             const float* __restrict__ cheb2,
                                             ushort16* __restrict__ xF,
                                             ushort16* __restrict__ cheb1F,
                                             ushort16* __restrict__ cheb2F,
                                             ushort16* __restrict__ coefF) {
    __shared__ __align__(16) uint32 Xs[128 * 64];   // [w][h-pair units swizzled]
    const int blk = blockIdx.x, tid = threadIdx.x;
    if (blk < 512) {
        const int bc = blk;
        const float* xp = x + (size_t)bc * (LEN * LEN);
        {
            int w = tid & 127, hg = tid >> 7;
            #pragma unroll
            for (int uu = 0; uu < 8; ++uu) {
                int u = hg * 8 + uu;
                uint4 d;
                uint32* dp = (uint32*)&d;
                #pragma unroll
                for (int t = 0; t < 4; ++t) {
                    int h2 = u * 4 + t;
                    dp[t] = pkbf(xp[(2 * h2) * LEN + w], xp[(2 * h2 + 1) * LEN + w]);
                }
                *(uint4*)(Xs + w * 64 + ((u ^ SIG(w)) << 2)) = d;
            }
        }
        __syncthreads();
        ushort16* dst = xF + (size_t)bc * 16384;
        #pragma unroll
        for (int i = 0; i < 8; ++i) {
            int n = tid + i * 256;               // 0..2047 fragment-units of 16B
            int lane = n & 63, fk = n >> 6;      // fk = mt*4+ks
            int wrow = (fk >> 2) * 16 + (lane & 15);
            int u = (fk & 3) * 4 + (lane >> 4);
            uint4 v = *(const uint4*)(Xs + wrow * 64 + ((u ^ SIG(wrow)) << 2));
            *(uint4*)(dst + (size_t)n * 8) = v;
        }
    } else {
        int i = (blk - 512) * 256 + tid;         // 0..171519
        if (i < 81920) {
            int j = i & 7, lane = (i >> 3) & 63, ks = (i >> 9) & 3, nt = i >> 11;
            int kp = nt * 16 + (lane & 15);
            int k = kp >> 7, p = kp & 127;
            int h = ks * 32 + ((lane >> 4) << 3) + j;
            cheb1F[i] = f2bf(cheb1[(k * LEN + h) * LEN + p]);
        } else if (i < 163840) {
            int i2 = i - 81920;
            int j = i2 & 7, lane = (i2 >> 3) & 63, t = i2 >> 9;
            int ks = t % 20, nt = t / 20;
            int q = nt * 16 + (lane & 15);
            int lw = ks * 32 + ((lane >> 4) << 3) + j;
            int l = lw >> 7, w = lw & 127;
            cheb2F[i2] = f2bf(cheb2[(l * LEN + w) * LEN + q]);
        } else {
            int i3 = i - 163840;
            int j = i3 & 7, lane = (i3 >> 3) & 63, t = i3 >> 9;
            int ks = t % 3, nt = t / 3;
            int lu = nt * 16 + (lane & 15);
            int l = lu >> 4, u = lu & 15;
            int kc = ks * 32 + ((lane >> 4) << 3) + j;
            int k = kc >> 4, c = kc & 15;
            coefF[i3] = (kc < KC) ? f2bf(coefs[((k * NK + l) * NC + c) * NU + u]) : (ushort16)0;
        }
    }
}

// ---------------- k1: t1[bl][p][kc][w] = sum_h cheb1[k][h][p]*x[b][c][h][w]
// grid (c, bl, nsp 0..3); block covers 2 ns segments of 80 kp with A-fragments
// (xF[b,c]) hoisted into registers and reused across both segments (halves xF
// L2 traffic). Verified structure (round 3).
__global__ __launch_bounds__(256, 4) void k1_mfma(const ushort16* __restrict__ xF,
                                                  const ushort16* __restrict__ cheb1F,
                                                  ushort16* __restrict__ t1, int b0) {
    __shared__ __align__(16) uint32 Bs[80 * 64];   // bounce: 80 kp-rows x 128 w bf16, swizzled
    const int c = blockIdx.x, bl = blockIdx.y, nsp = blockIdx.z;
    const int b = b0 + bl;
    const int tid = threadIdx.x;
    const int lane = tid & 63, wm = tid >> 6;      // wave = m-quarter
    const int m16 = lane & 15, g = lane >> 4;

    const ushort16* xFb = xF + ((size_t)(b * NC + c)) * 16384;

    bf16x8 Af[2][4];
    #pragma unroll
    for (int mi = 0; mi < 2; ++mi)
        #pragma unroll
        for (int ks = 0; ks < 4; ++ks) {
            int mt = wm * 2 + mi;
            Af[mi][ks] = frag16(xFb + ((size_t)(mt * 4 + ks) * 64 + lane) * 8);
        }

    #pragma unroll
    for (int s2 = 0; s2 < 2; ++s2) {
        const int ns = nsp * 2 + s2;
        f32x4 acc[2][5];
        #pragma unroll
        for (int mi = 0; mi < 2; ++mi)
            #pragma unroll
            for (int ni = 0; ni < 5; ++ni) acc[mi][ni] = (f32x4)0.f;

        #pragma unroll
        for (int ks = 0; ks < 4; ++ks) {
            bf16x8 Bf[5];
            #pragma unroll
            for (int ni = 0; ni < 5; ++ni)
                Bf[ni] = frag16(cheb1F + ((size_t)((ns * 5 + ni) * 4 + ks) * 64 + lane) * 8);
            #pragma unroll
            for (int mi = 0; mi < 2; ++mi)
                #pragma unroll
                for (int ni = 0; ni < 5; ++ni)
                    acc[mi][ni] = MFMA(Af[mi][ks], Bf[ni], acc[mi][ni]);
        }

        if (s2) __syncthreads();   // prev readout done before overwriting Bs

        // bounce: D element (m = w = wm*32+mi*16+g*4+r, n = rr = ni*16+m16)
        #pragma unroll
        for (int ni = 0; ni < 5; ++ni)
            #pragma unroll
            for (int mi = 0; mi < 2; ++mi) {
                int rr = ni * 16 + m16;
                int wu = wm * 32 + mi * 16 + g * 4;       // ushort col (w)
                uint2 d;
                d.x = pkbf(acc[mi][ni][0], acc[mi][ni][1]);
                d.y = pkbf(acc[mi][ni][2], acc[mi][ni][3]);
                int u = wu >> 3;
                *(uint2*)(Bs + rr * 64 + ((u ^ SIG(rr)) << 2) + ((wu >> 1) & 3)) = d;
            }
        __syncthreads();

        // read-out + coalesced store (256B runs)
        #pragma unroll
        for (int i = 0; i < 5; ++i) {
            int n = tid + i * 256;                 // 0..1279
            int rr = n >> 4, wsg = n & 15;
            uint4 v = *(const uint4*)(Bs + rr * 64 + ((wsg ^ SIG(rr)) << 2));
            int kp = ns * 80 + rr;
            int k = kp >> 7, p = kp & 127;
            *(uint4*)(t1 + ((size_t)((bl * LEN + p) * KC + k * NC + c)) * LEN + wsg * 8) = v;
        }
    }
}

// ---------------- k2: per (pg, bl) block, 2 p-slices (p = 2pg, 2pg+1)
// stage2 x2: s[w][lu] = Ts[w][kc] x coefF (acc in regs); stage3 M=32:
// out[pu][q] = A3[pu][lw] x cheb2F, K=640 — halves cheb2F/coefF L2 traffic.
// LDS: 10240 dw = 40960B exactly -> 4 blocks/CU. Ts (rows 0..127, stride 64dw)
// and compact A3 (32 rows, stride 320dw, swizzled units) alias the same buffer.
__global__ __launch_bounds__(256, 4) void k2_mfma(const ushort16* __restrict__ t1,
                                                  const ushort16* __restrict__ coefF,
                                                  const ushort16* __restrict__ cheb2F,
                                                  float* __restrict__ out, int b0) {
    __shared__ __align__(16) uint32 sm[10240];   // 40960 B
    const int pg = blockIdx.x, bl = blockIdx.y, b = b0 + bl;
    const int tid = threadIdx.x;
    const int lane = tid & 63, wave = tid >> 6;
    const int n16 = lane & 15, g = lane >> 4;

    const uint32* t1base = (const uint32*)(t1 + (size_t)(bl * LEN + 2 * pg) * (KC * LEN));

    // ---- issue p0 t1 loads FIRST
    uint4 Av[3], Bv[3];
    #pragma unroll
    for (int i = 0; i < 3; ++i) {
        int it = tid + i * 256;
        if (it < 640) {
            int a2 = it >> 4, wq = it & 15;
            const uint32* src = t1base + a2 * 128 + wq * 4;
            Av[i] = *(const uint4*)(src);
            Bv[i] = *(const uint4*)(src + 64);
        }
    }
    // zero K-pad (units 10,11 = kc 80..95) while loads in flight; persists both stage2s
    #pragma unroll
    for (int i = 0; i < 4; ++i) {
        int idx = tid + i * 256;             // 0..1023
        int row = idx >> 3, d = idx & 7;
        int u = 10 + (d >> 2);
        sm[row * 64 + ((u ^ SIG(row)) << 2) + (d & 3)] = 0;
    }
    // ---- write Ts(p0)
    #pragma unroll
    for (int i = 0; i < 3; ++i) {
        int it = tid + i * 256;
        if (it < 640) {
            int a2 = it >> 4, wq = it & 15;
            const uint32* av = (const uint32*)&Av[i];
            const uint32* bv = (const uint32*)&Bv[i];
            int u = a2 >> 2, lo = a2 & 3;
            #pragma unroll
            for (int j = 0; j < 4; ++j) {
                int r0 = wq * 8 + 2 * j, r1 = r0 + 1;
                sm[r0 * 64 + ((u ^ SIG(r0)) << 2) + lo] = (av[j] & 0xffffu) | (bv[j] << 16);
                sm[r1 * 64 + ((u ^ SIG(r1)) << 2) + lo] = (av[j] >> 16) | (bv[j] & 0xffff0000u);
            }
        }
    }
    __syncthreads();

    // ---- issue p1 t1 loads (latency hides under stage2(p0))
    #pragma unroll
    for (int i = 0; i < 3; ++i) {
        int it = tid + i * 256;
        if (it < 640) {
            int a2 = it >> 4, wq = it & 15;
            const uint32* src = t1base + 5120 + a2 * 128 + wq * 4;
            Av[i] = *(const uint4*)(src);
            Bv[i] = *(const uint4*)(src + 64);
        }
    }

    f32x4 acc[2][2][5];
    #pragma unroll
    for (int pi = 0; pi < 2; ++pi)
        #pragma unroll
        for (int mi = 0; mi < 2; ++mi)
            #pragma unroll
            for (int ni = 0; ni < 5; ++ni) acc[pi][mi][ni] = (f32x4)0.f;

    // ---- stage2(p0)
    #pragma unroll
    for (int ks = 0; ks < 3; ++ks) {
        bf16x8 Af[2], Bf[5];
        #pragma unroll
        for (int mi = 0; mi < 2; ++mi) {
            int row = wave * 32 + mi * 16 + n16;
            Af[mi] = frag16(sm + row * 64 + (((ks * 4 + g) ^ SIG(row)) << 2));
        }
        #pragma unroll
        for (int ni = 0; ni < 5; ++ni)
            Bf[ni] = frag16(coefF + ((size_t)(ni * 3 + ks) * 64 + lane) * 8);
        #pragma unroll
        for (int mi = 0; mi < 2; ++mi)
            #pragma unroll
            for (int ni = 0; ni < 5; ++ni)
                acc[0][mi][ni] = MFMA(Af[mi], Bf[ni], acc[0][mi][ni]);
    }
    __syncthreads();

    // ---- write Ts(p1)
    #pragma unroll
    for (int i = 0; i < 3; ++i) {
        int it = tid + i * 256;
        if (it < 640) {
            int a2 = it >> 4, wq = it & 15;
            const uint32* av = (const uint32*)&Av[i];
            const uint32* bv = (const uint32*)&Bv[i];
            int u = a2 >> 2, lo = a2 & 3;
            #pragma unroll
            for (int j = 0; j < 4; ++j) {
                int r0 = wq * 8 + 2 * j, r1 = r0 + 1;
                sm[r0 * 64 + ((u ^ SIG(r0)) << 2) + lo] = (av[j] & 0xffffu) | (bv[j] << 16);
                sm[r1 * 64 + ((u ^ SIG(r1)) << 2) + lo] = (av[j] >> 16) | (bv[j] & 0xffff0000u);
            }
        }
    }
    __syncthreads();

    // ---- stage2(p1)
    #pragma unroll
    for (int ks = 0; ks < 3; ++ks) {
        bf16x8 Af[2], Bf[5];
        #pragma unroll
        for (int mi = 0; mi < 2; ++mi) {
            int row = wave * 32 + mi * 16 + n16;
            Af[mi] = frag16(sm + row * 64 + (((ks * 4 + g) ^ SIG(row)) << 2));
        }
        #pragma unroll
        for (int ni = 0; ni < 5; ++ni)
            Bf[ni] = frag16(coefF + ((size_t)(ni * 3 + ks) * 64 + lane) * 8);
        #pragma unroll
        for (int mi = 0; mi < 2; ++mi)
            #pragma unroll
            for (int ni = 0; ni < 5; ++ni)
                acc[1][mi][ni] = MFMA(Af[mi], Bf[ni], acc[1][mi][ni]);
    }
    __syncthreads();   // Ts fully dead; compact A3 overwrites

    // ---- A3 compact: row pu = pi*16+u (u=n16), stride 320 dw, swizzled 16B units
    #pragma unroll
    for (int pi = 0; pi < 2; ++pi)
        #pragma unroll
        for (int mi = 0; mi < 2; ++mi)
            #pragma unroll
            for (int ni = 0; ni < 5; ++ni) {
                int row = pi * 16 + n16;
                int col = ni * 128 + wave * 32 + mi * 16 + g * 4;   // ushort col (lw)
                int u = col >> 3;
                uint2 d;
                d.x = pkbf(acc[pi][mi][ni][0], acc[pi][mi][ni][1]);
                d.y = pkbf(acc[pi][mi][ni][2], acc[pi][mi][ni][3]);
                *(uint2*)(sm + row * 320 + ((u ^ SIG(row)) << 2) + (g & 1) * 2) = d;
            }
    __syncthreads();

    // ---- stage3: M=32 (pu), wave owns 32 q
    f32x4 c3[2][2];
    c3[0][0] = (f32x4)0.f; c3[0][1] = (f32x4)0.f;
    c3[1][0] = (f32x4)0.f; c3[1][1] = (f32x4)0.f;
    #pragma unroll 5
    for (int ks = 0; ks < 20; ++ks) {
        bf16x8 Af2[2], Bf2[2];
        #pragma unroll
        for (int mi = 0; mi < 2; ++mi) {
            int row = mi * 16 + n16;
            Af2[mi] = frag16(sm + row * 320 + (((ks * 4 + g) ^ SIG(row)) << 2));
        }
        #pragma unroll
        for (int nt = 0; nt < 2; ++nt)
            Bf2[nt] = frag16(cheb2F + ((size_t)((wave * 2 + nt) * 20 + ks) * 64 + lane) * 8);
        #pragma unroll
        for (int mi = 0; mi < 2; ++mi)
            #pragma unroll
            for (int nt = 0; nt < 2; ++nt)
                c3[mi][nt] = MFMA(Af2[mi], Bf2[nt], c3[mi][nt]);
    }

    #pragma unroll
    for (int mi = 0; mi < 2; ++mi)
        #pragma unroll
        for (int nt = 0; nt < 2; ++nt)
            #pragma unroll
            for (int r = 0; r < 4; ++r) {
                int u = g * 4 + r;
                int q = wave * 32 + nt * 16 + n16;
                out[(((size_t)(b * NU + u)) * LEN + (2 * pg + mi)) * LEN + q] = c3[mi][nt][r];
            }
}

extern "C" void kernel_launch(void* const* d_in, const int* in_sizes, int n_in,
                              void* d_out, int out_size, void* d_ws, size_t ws_size,
                              hipStream_t stream) {
    const float* x     = (const float*)d_in[0];
    const float* coefs = (const float*)d_in[1];
    const float* cheb1 = (const float*)d_in[2];
    const float* cheb2 = (const float*)d_in[3];
    float* out = (float*)d_out;

    const size_t xF_bytes  = (size_t)NB * NC * 16384 * sizeof(ushort16);   // 16.8 MB
    const size_t aux_bytes = 163840 + 163840 + 15360;                      // cheb1F + cheb2F + coefF
    size_t off = (ws_size - aux_bytes - xF_bytes) & ~(size_t)255;
    ushort16* cheb1F = (ushort16*)((char*)d_ws + off);
    ushort16* cheb2F = cheb1F + 81920;
    ushort16* coefF  = cheb2F + 81920;
    ushort16* xF     = coefF + 7680;
    ushort16* t1 = (ushort16*)d_ws;

    const size_t per_b = (size_t)LEN * KC * LEN * sizeof(ushort16);        // 2.62 MB
    int chunk = (int)(off / per_b);
    if (chunk < 1) chunk = 1;
    if (chunk > NB) chunk = NB;

    hipLaunchKernelGGL(kprep, dim3(1182), dim3(256), 0, stream,
                       x, coefs, cheb1, cheb2, xF, cheb1F, cheb2F, coefF);
    for (int b0 = 0; b0 < NB; b0 += chunk) {
        int cb = (NB - b0 < chunk) ? (NB - b0) : chunk;
        hipLaunchKernelGGL(k1_mfma, dim3(NC, cb, 4), dim3(256), 0, stream,
                           xF, cheb1F, t1, b0);
        hipLaunchKernelGGL(k2_mfma, dim3(64, cb), dim3(256), 0, stream,
                           t1, coefF, cheb2F, out, b0);
    }
}

// Round 7
// 146.935 us; speedup vs baseline: 1.1228x; 1.1228x over previous
//
#include <hip/hip_runtime.h>
#include <hip/hip_bf16.h>

#define LEN 128
#define NB 32
#define NC 16
#define NU 16
#define NK 5
#define KC 80          // (k,c) pairs
#define KCP 96         // padded K for stage2

typedef unsigned int uint32;
typedef unsigned short ushort16;
typedef __attribute__((ext_vector_type(8))) short bf16x8;
typedef __attribute__((ext_vector_type(4))) float f32x4;

#define MFMA(a, b, c) __builtin_amdgcn_mfma_f32_16x16x32_bf16(a, b, c, 0, 0, 0)

// XOR swizzle of the 16B-unit index within a 64-dword row (16 units).
#define SIG(r) (((r) & 15) ^ (((r) >> 3) & 15))

static __device__ inline ushort16 f2bf(float f) {
    union { float f; uint32 u; } v; v.f = f;
    uint32 u = v.u;
    uint32 r = (u + 0x7fffu + ((u >> 16) & 1u)) >> 16;   // RNE
    return (ushort16)r;
}
static __device__ inline uint32 pkbf(float a, float b) {   // low=a, high=b (verified r0-r5)
    return (uint32)f2bf(a) | ((uint32)f2bf(b) << 16);
}
static __device__ inline bf16x8 frag16(const void* p) {    // 16B-aligned
    return *(const bf16x8*)p;
}

// ---------------- kprep: blocks 0..511 = x->xF transpose; 512..1181 = const operands ----------------
__global__ __launch_bounds__(256) void kprep(const float* __restrict__ x,
                                             const float* __restrict__ coefs,
                                             const float* __restrict__ cheb1,
                                             const float* __restrict__ cheb2,
                                             ushort16* __restrict__ xF,
                                             ushort16* __restrict__ cheb1F,
                                             ushort16* __restrict__ cheb2F,
                                             ushort16* __restrict__ coefF) {
    __shared__ __align__(16) uint32 Xs[128 * 64];   // [w][h-pair units swizzled]
    const int blk = blockIdx.x, tid = threadIdx.x;
    if (blk < 512) {
        const int bc = blk;
        const float* xp = x + (size_t)bc * (LEN * LEN);
        {
            int w = tid & 127, hg = tid >> 7;
            #pragma unroll
            for (int uu = 0; uu < 8; ++uu) {
                int u = hg * 8 + uu;
                uint4 d;
                uint32* dp = (uint32*)&d;
                #pragma unroll
                for (int t = 0; t < 4; ++t) {
                    int h2 = u * 4 + t;
                    dp[t] = pkbf(xp[(2 * h2) * LEN + w], xp[(2 * h2 + 1) * LEN + w]);
                }
                *(uint4*)(Xs + w * 64 + ((u ^ SIG(w)) << 2)) = d;
            }
        }
        __syncthreads();
        ushort16* dst = xF + (size_t)bc * 16384;
        #pragma unroll
        for (int i = 0; i < 8; ++i) {
            int n = tid + i * 256;               // 0..2047 fragment-units of 16B
            int lane = n & 63, fk = n >> 6;      // fk = mt*4+ks
            int wrow = (fk >> 2) * 16 + (lane & 15);
            int u = (fk & 3) * 4 + (lane >> 4);
            uint4 v = *(const uint4*)(Xs + wrow * 64 + ((u ^ SIG(wrow)) << 2));
            *(uint4*)(dst + (size_t)n * 8) = v;
        }
    } else {
        int i = (blk - 512) * 256 + tid;         // 0..171519
        if (i < 81920) {
            int j = i & 7, lane = (i >> 3) & 63, ks = (i >> 9) & 3, nt = i >> 11;
            int kp = nt * 16 + (lane & 15);
            int k = kp >> 7, p = kp & 127;
            int h = ks * 32 + ((lane >> 4) << 3) + j;
            cheb1F[i] = f2bf(cheb1[(k * LEN + h) * LEN + p]);
        } else if (i < 163840) {
            int i2 = i - 81920;
            int j = i2 & 7, lane = (i2 >> 3) & 63, t = i2 >> 9;
            int ks = t % 20, nt = t / 20;
            int q = nt * 16 + (lane & 15);
            int lw = ks * 32 + ((lane >> 4) << 3) + j;
            int l = lw >> 7, w = lw & 127;
            cheb2F[i2] = f2bf(cheb2[(l * LEN + w) * LEN + q]);
        } else {
            int i3 = i - 163840;
            int j = i3 & 7, lane = (i3 >> 3) & 63, t = i3 >> 9;
            int ks = t % 3, nt = t / 3;
            int lu = nt * 16 + (lane & 15);
            int l = lu >> 4, u = lu & 15;
            int kc = ks * 32 + ((lane >> 4) << 3) + j;
            int k = kc >> 4, c = kc & 15;
            coefF[i3] = (kc < KC) ? f2bf(coefs[((k * NK + l) * NC + c) * NU + u]) : (ushort16)0;
        }
    }
}

// ---------------- k1: t1[bl][p][kc][w] = sum_h cheb1[k][h][p]*x[b][c][h][w]
// grid (c, bl, ns 0..7); ns = 80-kp segment. LDS-free GEMM: both operands read
// as wave-contiguous 1KB fragments from global. Epilogue bounces through 20KB
// LDS so t1 stores are 256B-coalesced runs. 5 blocks/CU for latency hiding.
__global__ __launch_bounds__(256, 5) void k1_mfma(const ushort16* __restrict__ xF,
                                                  const ushort16* __restrict__ cheb1F,
                                                  ushort16* __restrict__ t1, int b0) {
    __shared__ __align__(16) uint32 Bs[80 * 64];   // bounce: 80 kp-rows x 128 w bf16, swizzled
    const int c = blockIdx.x, bl = blockIdx.y, ns = blockIdx.z;
    const int b = b0 + bl;
    const int tid = threadIdx.x;
    const int lane = tid & 63, wm = tid >> 6;      // wave = m-quarter
    const int m16 = lane & 15, g = lane >> 4;

    const ushort16* xFb = xF + ((size_t)(b * NC + c)) * 16384;

    f32x4 acc[2][5];
    #pragma unroll
    for (int mi = 0; mi < 2; ++mi)
        #pragma unroll
        for (int ni = 0; ni < 5; ++ni) acc[mi][ni] = (f32x4)0.f;

    #pragma unroll
    for (int ks = 0; ks < 4; ++ks) {
        bf16x8 Af[2], Bf[5];
        #pragma unroll
        for (int mi = 0; mi < 2; ++mi) {
            int mt = wm * 2 + mi;
            Af[mi] = frag16(xFb + ((size_t)(mt * 4 + ks) * 64 + lane) * 8);
        }
        #pragma unroll
        for (int ni = 0; ni < 5; ++ni) {
            int nt = ns * 5 + ni;
            Bf[ni] = frag16(cheb1F + ((size_t)(nt * 4 + ks) * 64 + lane) * 8);
        }
        #pragma unroll
        for (int mi = 0; mi < 2; ++mi)
            #pragma unroll
            for (int ni = 0; ni < 5; ++ni)
                acc[mi][ni] = MFMA(Af[mi], Bf[ni], acc[mi][ni]);
    }

    // bounce: D element (m = w = wm*32+mi*16+g*4+r, n = rr = ni*16+m16)
    #pragma unroll
    for (int ni = 0; ni < 5; ++ni)
        #pragma unroll
        for (int mi = 0; mi < 2; ++mi) {
            int rr = ni * 16 + m16;
            int wu = wm * 32 + mi * 16 + g * 4;       // ushort col (w)
            uint2 d;
            d.x = pkbf(acc[mi][ni][0], acc[mi][ni][1]);
            d.y = pkbf(acc[mi][ni][2], acc[mi][ni][3]);
            int u = wu >> 3;
            *(uint2*)(Bs + rr * 64 + ((u ^ SIG(rr)) << 2) + ((wu >> 1) & 3)) = d;
        }
    __syncthreads();

    // read-out + coalesced store (256B runs)
    #pragma unroll
    for (int i = 0; i < 5; ++i) {
        int n = tid + i * 256;                 // 0..1279
        int rr = n >> 4, wsg = n & 15;
        uint4 v = *(const uint4*)(Bs + rr * 64 + ((wsg ^ SIG(rr)) << 2));
        int kp = ns * 80 + rr;
        int k = kp >> 7, p = kp & 127;
        *(uint4*)(t1 + ((size_t)((bl * LEN + p) * KC + k * NC + c)) * LEN + wsg * 8) = v;
    }
}

// ---------------- k2: per (p, bl) block (1 p-slice => 32KB LDS => 5 blocks/CU)
// stage2: s[w(128)][lu(80)] = Ts[w][kc] x coefF, K=96 (zero-padded)
// stage3: out[u(16)][q(128)] = A3[u][lw] x cheb2F, K=640; l=0 block of cheb2 is
// the IDENTITY (T_0 = I) -> skip ks 0..3 (K eff 512) and add A3[u][q] in epilogue.
__global__ __launch_bounds__(256, 5) void k2_mfma(const ushort16* __restrict__ t1,
                                                  const ushort16* __restrict__ coefF,
                                                  const ushort16* __restrict__ cheb2F,
                                                  float* __restrict__ out, int b0) {
    __shared__ __align__(16) uint32 sm[128 * 64];   // 32KB: Ts [w][kc units swz]; A3 (16x648 ush) aliases
    const int p = blockIdx.x, bl = blockIdx.y, b = b0 + bl;
    const int tid = threadIdx.x;
    const int lane = tid & 63, wave = tid >> 6;
    const int n16 = lane & 15, g = lane >> 4;

    // issue t1 global loads FIRST (longest latency in the chain)
    const uint32* t1u = (const uint32*)(t1 + (size_t)(bl * LEN + p) * (KC * LEN));
    uint4 Av[3], Bv[3];
    #pragma unroll
    for (int i = 0; i < 3; ++i) {
        int it = tid + i * 256;              // 0..639 active
        if (it < 640) {
            int a2 = it >> 4, wq = it & 15;  // a2 = kc-pair 0..39
            const uint32* src = t1u + a2 * 128 + wq * 4;
            Av[i] = *(const uint4*)(src);
            Bv[i] = *(const uint4*)(src + 64);
        }
    }
    // zero K-pad (dw 40..47 = units 10,11) while loads are in flight
    #pragma unroll
    for (int i = 0; i < 4; ++i) {
        int idx = tid + i * 256;             // 0..1023
        int row = idx >> 3, d = idx & 7;
        int u = 10 + (d >> 2);
        sm[row * 64 + ((u ^ SIG(row)) << 2) + (d & 3)] = 0;
    }
    // transpose kc-pairs into swizzled rows (verified shift/mask merges)
    #pragma unroll
    for (int i = 0; i < 3; ++i) {
        int it = tid + i * 256;
        if (it < 640) {
            int a2 = it >> 4, wq = it & 15;
            const uint32* av = (const uint32*)&Av[i];
            const uint32* bv = (const uint32*)&Bv[i];
            int u = a2 >> 2, lo = a2 & 3;
            #pragma unroll
            for (int j = 0; j < 4; ++j) {
                int r0 = wq * 8 + 2 * j, r1 = r0 + 1;
                sm[r0 * 64 + ((u ^ SIG(r0)) << 2) + lo] = (av[j] & 0xffffu) | (bv[j] << 16);
                sm[r1 * 64 + ((u ^ SIG(r1)) << 2) + lo] = (av[j] >> 16) | (bv[j] & 0xffff0000u);
            }
        }
    }
    __syncthreads();

    // ---- stage2: rows w = wave*32 + mi*16 + n16
    f32x4 acc[2][5];
    #pragma unroll
    for (int mi = 0; mi < 2; ++mi)
        #pragma unroll
        for (int ni = 0; ni < 5; ++ni) acc[mi][ni] = (f32x4)0.f;

    #pragma unroll
    for (int ks = 0; ks < 3; ++ks) {
        bf16x8 Af[2], Bf[5];
        #pragma unroll
        for (int mi = 0; mi < 2; ++mi) {
            int row = wave * 32 + mi * 16 + n16;
            Af[mi] = frag16(sm + row * 64 + (((ks * 4 + g) ^ SIG(row)) << 2));
        }
        #pragma unroll
        for (int ni = 0; ni < 5; ++ni)
            Bf[ni] = frag16(coefF + ((size_t)(ni * 3 + ks) * 64 + lane) * 8);
        #pragma unroll
        for (int mi = 0; mi < 2; ++mi)
            #pragma unroll
            for (int ni = 0; ni < 5; ++ni)
                acc[mi][ni] = MFMA(Af[mi], Bf[ni], acc[mi][ni]);
    }
    __syncthreads();   // Ts reads done; A3 may overwrite

    // s -> A3: row u = n16 (16 rows, stride 648 ushort), col l*128+w
    {
        ushort16* A3 = (ushort16*)sm;
        #pragma unroll
        for (int mi = 0; mi < 2; ++mi)
            #pragma unroll
            for (int ni = 0; ni < 5; ++ni) {
                int wcol = wave * 32 + mi * 16 + g * 4;
                uint2 d;
                d.x = pkbf(acc[mi][ni][0], acc[mi][ni][1]);
                d.y = pkbf(acc[mi][ni][2], acc[mi][ni][3]);
                *(uint2*)(A3 + n16 * 648 + ni * 128 + wcol) = d;
            }
    }
    __syncthreads();

    // ---- stage3: M=16 (u), wave owns 32 q. Skip l=0 (identity): ks 4..19 only.
    const ushort16* A3r = (const ushort16*)sm;
    f32x4 c3[2];
    c3[0] = (f32x4)0.f; c3[1] = (f32x4)0.f;
    #pragma unroll 4
    for (int ks = 4; ks < 20; ++ks) {
        bf16x8 Aa = frag16(A3r + n16 * 648 + ks * 32 + g * 8);
        #pragma unroll
        for (int nt = 0; nt < 2; ++nt) {
            bf16x8 Bb = frag16(cheb2F + ((size_t)((wave * 2 + nt) * 20 + ks) * 64 + lane) * 8);
            c3[nt] = MFMA(Aa, Bb, c3[nt]);
        }
    }

    #pragma unroll
    for (int nt = 0; nt < 2; ++nt)
        #pragma unroll
        for (int r = 0; r < 4; ++r) {
            int u = g * 4 + r;
            int q = wave * 32 + nt * 16 + n16;
            // l=0 identity contribution: + s[u][w=q] (bf16 in A3 col q)
            uint32 bf = ((uint32)A3r[u * 648 + q]) << 16;
            float l0 = __uint_as_float(bf);
            out[(((size_t)(b * NU + u)) * LEN + p) * LEN + q] = c3[nt][r] + l0;
        }
}

extern "C" void kernel_launch(void* const* d_in, const int* in_sizes, int n_in,
                              void* d_out, int out_size, void* d_ws, size_t ws_size,
                              hipStream_t stream) {
    const float* x     = (const float*)d_in[0];
    const float* coefs = (const float*)d_in[1];
    const float* cheb1 = (const float*)d_in[2];
    const float* cheb2 = (const float*)d_in[3];
    float* out = (float*)d_out;

    const size_t xF_bytes  = (size_t)NB * NC * 16384 * sizeof(ushort16);   // 16.8 MB
    const size_t aux_bytes = 163840 + 163840 + 15360;                      // cheb1F + cheb2F + coefF
    size_t off = (ws_size - aux_bytes - xF_bytes) & ~(size_t)255;
    ushort16* cheb1F = (ushort16*)((char*)d_ws + off);
    ushort16* cheb2F = cheb1F + 81920;
    ushort16* coefF  = cheb2F + 81920;
    ushort16* xF     = coefF + 7680;
    ushort16* t1 = (ushort16*)d_ws;

    const size_t per_b = (size_t)LEN * KC * LEN * sizeof(ushort16);        // 2.62 MB
    int chunk = (int)(off / per_b);
    if (chunk < 1) chunk = 1;
    if (chunk > NB) chunk = NB;

    hipLaunchKernelGGL(kprep, dim3(1182), dim3(256), 0, stream,
                       x, coefs, cheb1, cheb2, xF, cheb1F, cheb2F, coefF);
    for (int b0 = 0; b0 < NB; b0 += chunk) {
        int cb = (NB - b0 < chunk) ? (NB - b0) : chunk;
        hipLaunchKernelGGL(k1_mfma, dim3(NC, cb, 8), dim3(256), 0, stream,
                           xF, cheb1F, t1, b0);
        hipLaunchKernelGGL(k2_mfma, dim3(LEN, cb), dim3(256), 0, stream,
                           t1, coefF, cheb2F, out, b0);
    }
}